// Round 3
// baseline (35.871 us; speedup 1.0000x reference)
//
#include <hip/hip_runtime.h>
#include <hip/hip_cooperative_groups.h>

namespace cg = cooperative_groups;

#define NBLK 256   // 1 block per CU -> cooperative co-residency guaranteed
#define NTHR 256
#define PER_THREAD 2   // NBLK*NTHR*PER_THREAD == n4 == 131072

// Fused: weighted sums S = sum(w*e), S2 = sum(w*e^2), e=(y-y_hat)^2,
// w = (row index along dim1)+1; grid barrier; block 0 finishes variance.
__global__ __launch_bounds__(NTHR) void stoch_fused(
    const float4* __restrict__ y,
    const float4* __restrict__ yh,
    double* __restrict__ ws,
    float* __restrict__ out,
    double M, int n4)
{
    cg::grid_group grid = cg::this_grid();

    int tid = blockIdx.x * NTHR + threadIdx.x;
    double s = 0.0, s2 = 0.0;

    #pragma unroll
    for (int p = 0; p < PER_THREAD; ++p) {
        int idx = tid + p * (NBLK * NTHR);
        if (idx < n4) {
            float4 a = y[idx];
            float4 b = yh[idx];
            // Layout: [B][N=1024][D=64] fp32 -> 16 float4 per (b,i) row.
            int i = (idx >> 4) & 1023;
            double w = (double)(i + 1);
            float d0 = a.x - b.x, d1 = a.y - b.y, d2 = a.z - b.z, d3 = a.w - b.w;
            float e0 = d0 * d0, e1 = d1 * d1, e2 = d2 * d2, e3 = d3 * d3;
            s  += w * ((double)e0 + (double)e1 + (double)e2 + (double)e3);
            s2 += w * ((double)e0 * e0 + (double)e1 * e1
                     + (double)e2 * e2 + (double)e3 * e3);
        }
    }

    // wave-64 butterfly reduce
    #pragma unroll
    for (int off = 32; off > 0; off >>= 1) {
        s  += __shfl_down(s,  off, 64);
        s2 += __shfl_down(s2, off, 64);
    }

    __shared__ double sh[2][NTHR / 64];
    {
        int wave = threadIdx.x >> 6;
        int lane = threadIdx.x & 63;
        if (lane == 0) { sh[0][wave] = s; sh[1][wave] = s2; }
    }
    __syncthreads();

    if (threadIdx.x == 0) {
        double ts = 0.0, ts2 = 0.0;
        #pragma unroll
        for (int wv = 0; wv < NTHR / 64; ++wv) { ts += sh[0][wv]; ts2 += sh[1][wv]; }
        ws[2 * blockIdx.x]     = ts;
        ws[2 * blockIdx.x + 1] = ts2;
    }

    grid.sync();   // all block partials visible device-wide after this

    if (blockIdx.x == 0) {
        // NTHR == NBLK: one partial pair per thread
        double a  = ws[2 * threadIdx.x];
        double b2 = ws[2 * threadIdx.x + 1];

        #pragma unroll
        for (int off = 32; off > 0; off >>= 1) {
            a  += __shfl_down(a,  off, 64);
            b2 += __shfl_down(b2, off, 64);
        }

        int wave = threadIdx.x >> 6;
        int lane = threadIdx.x & 63;
        if (lane == 0) { sh[0][wave] = a; sh[1][wave] = b2; }
        __syncthreads();

        if (threadIdx.x == 0) {
            double S = 0.0, S2 = 0.0;
            #pragma unroll
            for (int wv = 0; wv < NTHR / 64; ++wv) { S += sh[0][wv]; S2 += sh[1][wv]; }
            double var = (S2 - S * S / M) / (M - 1.0);
            out[0] = (float)var;
        }
    }
}

extern "C" void kernel_launch(void* const* d_in, const int* in_sizes, int n_in,
                              void* d_out, int out_size, void* d_ws, size_t ws_size,
                              hipStream_t stream) {
    const float4* y  = (const float4*)d_in[0];
    const float4* yh = (const float4*)d_in[1];
    double* ws = (double*)d_ws;
    float* out = (float*)d_out;

    int n_elem = in_sizes[0];          // B*N*D = 8*1024*64 = 524288
    int n4 = n_elem / 4;               // 131072

    // M = B * N(N+1)/2 * D  (static expanded length of the repeat)
    const double B = 8.0, N = 1024.0, D = 64.0;
    double M = B * (N * (N + 1.0) * 0.5) * D;   // 268,697,600

    void* args[] = { (void*)&y, (void*)&yh, (void*)&ws, (void*)&out,
                     (void*)&M, (void*)&n4 };
    hipLaunchCooperativeKernel((const void*)stoch_fused,
                               dim3(NBLK), dim3(NTHR), args, 0, stream);
}

// Round 4
// 21.104 us; speedup vs baseline: 1.6997x; 1.6997x over previous
//
#include <hip/hip_runtime.h>

#define NBLK 512
#define NTHR 256   // NBLK*NTHR == n4 == 131072 (one float4 per thread)

// Single fused kernel: per-block weighted partial sums -> agent-scope stores;
// last block (atomic counter) reduces all pairs and writes the variance.
__global__ __launch_bounds__(NTHR) void stoch_fused(
    const float4* __restrict__ y,
    const float4* __restrict__ yh,
    unsigned int* __restrict__ cnt,
    double* __restrict__ pairs,
    float* __restrict__ out,
    double M, int n4)
{
    int idx = blockIdx.x * NTHR + threadIdx.x;
    double s = 0.0, s2 = 0.0;

    if (idx < n4) {
        float4 a = y[idx];
        float4 b = yh[idx];
        // Layout: [B][N=1024][D=64] fp32 -> 16 float4 per (b,i) row.
        int i = (idx >> 4) & 1023;
        double w = (double)(i + 1);
        float d0 = a.x - b.x, d1 = a.y - b.y, d2 = a.z - b.z, d3 = a.w - b.w;
        float e0 = d0 * d0, e1 = d1 * d1, e2 = d2 * d2, e3 = d3 * d3;
        s  = w * ((double)e0 + (double)e1 + (double)e2 + (double)e3);
        s2 = w * ((double)e0 * e0 + (double)e1 * e1
                + (double)e2 * e2 + (double)e3 * e3);
    }

    // wave-64 butterfly reduce
    #pragma unroll
    for (int off = 32; off > 0; off >>= 1) {
        s  += __shfl_down(s,  off, 64);
        s2 += __shfl_down(s2, off, 64);
    }

    __shared__ double sh[2][NTHR / 64];
    __shared__ int islast;
    int wave = threadIdx.x >> 6;
    int lane = threadIdx.x & 63;
    if (lane == 0) { sh[0][wave] = s; sh[1][wave] = s2; }
    __syncthreads();

    if (threadIdx.x == 0) {
        double ts = 0.0, ts2 = 0.0;
        #pragma unroll
        for (int wv = 0; wv < NTHR / 64; ++wv) { ts += sh[0][wv]; ts2 += sh[1][wv]; }
        // agent-scope stores: visible device-wide (bypass non-coherent XCD L2)
        __hip_atomic_store(&pairs[2 * blockIdx.x],     ts,
                           __ATOMIC_RELAXED, __HIP_MEMORY_SCOPE_AGENT);
        __hip_atomic_store(&pairs[2 * blockIdx.x + 1], ts2,
                           __ATOMIC_RELAXED, __HIP_MEMORY_SCOPE_AGENT);
        unsigned old = __hip_atomic_fetch_add(cnt, 1u,
                           __ATOMIC_ACQ_REL, __HIP_MEMORY_SCOPE_AGENT);
        islast = (old == NBLK - 1);
    }
    __syncthreads();

    if (islast) {
        // All 512 partial pairs are visible (release-chain via the counter).
        double a = 0.0, b = 0.0;
        #pragma unroll
        for (int p = 0; p < NBLK / NTHR; ++p) {
            int q = threadIdx.x + p * NTHR;
            a += __hip_atomic_load(&pairs[2 * q],
                                   __ATOMIC_RELAXED, __HIP_MEMORY_SCOPE_AGENT);
            b += __hip_atomic_load(&pairs[2 * q + 1],
                                   __ATOMIC_RELAXED, __HIP_MEMORY_SCOPE_AGENT);
        }
        #pragma unroll
        for (int off = 32; off > 0; off >>= 1) {
            a += __shfl_down(a, off, 64);
            b += __shfl_down(b, off, 64);
        }
        if (lane == 0) { sh[0][wave] = a; sh[1][wave] = b; }
        __syncthreads();
        if (threadIdx.x == 0) {
            double S = 0.0, S2 = 0.0;
            #pragma unroll
            for (int wv = 0; wv < NTHR / 64; ++wv) { S += sh[0][wv]; S2 += sh[1][wv]; }
            out[0] = (float)((S2 - S * S / M) / (M - 1.0));
        }
    }
}

extern "C" void kernel_launch(void* const* d_in, const int* in_sizes, int n_in,
                              void* d_out, int out_size, void* d_ws, size_t ws_size,
                              hipStream_t stream) {
    const float4* y  = (const float4*)d_in[0];
    const float4* yh = (const float4*)d_in[1];
    unsigned int* cnt = (unsigned int*)d_ws;                    // 4 B, memset to 0
    double* pairs = (double*)((char*)d_ws + 128);               // 512 pairs
    float* out = (float*)d_out;

    int n_elem = in_sizes[0];          // B*N*D = 8*1024*64 = 524288
    int n4 = n_elem / 4;               // 131072

    // M = B * N(N+1)/2 * D  (static expanded length of the repeat)
    const double B = 8.0, N = 1024.0, D = 64.0;
    double M = B * (N * (N + 1.0) * 0.5) * D;   // 268,697,600

    hipMemsetAsync(d_ws, 0, 4, stream);         // zero the arrival counter
    stoch_fused<<<NBLK, NTHR, 0, stream>>>(y, yh, cnt, pairs, out, M, n4);
}

// Round 5
// 13.086 us; speedup vs baseline: 2.7411x; 1.6127x over previous
//
#include <hip/hip_runtime.h>

#define NBLK 512
#define NTHR 256   // NBLK*NTHR == n4 == 131072 (one float4 per thread)

// Single fused kernel, no init node needed.
// Per-block flag increment scheme: all flags start from a UNIFORM value
// (fresh-alloc zeros or harness 0xAA poison); each call every block adds 1 to
// its own flag, so after block b's increment flags[b] == start + call_count
// for all b. Block 0 knows its own value v and spins until all flags reach v
// (wraparound-safe signed compare, bounded), then reduces all pairs.
__global__ __launch_bounds__(NTHR) void stoch_fused(
    const float4* __restrict__ y,
    const float4* __restrict__ yh,
    unsigned int* __restrict__ flags,
    double* __restrict__ pairs,
    float* __restrict__ out,
    double M, int n4)
{
    int idx = blockIdx.x * NTHR + threadIdx.x;
    double s = 0.0, s2 = 0.0;

    if (idx < n4) {
        float4 a = y[idx];
        float4 b = yh[idx];
        // Layout: [B][N=1024][D=64] fp32 -> 16 float4 per (b,i) row.
        int i = (idx >> 4) & 1023;
        double w = (double)(i + 1);
        float d0 = a.x - b.x, d1 = a.y - b.y, d2 = a.z - b.z, d3 = a.w - b.w;
        float e0 = d0 * d0, e1 = d1 * d1, e2 = d2 * d2, e3 = d3 * d3;
        s  = w * ((double)e0 + (double)e1 + (double)e2 + (double)e3);
        s2 = w * ((double)e0 * e0 + (double)e1 * e1
                + (double)e2 * e2 + (double)e3 * e3);
    }

    // wave-64 butterfly reduce
    #pragma unroll
    for (int off = 32; off > 0; off >>= 1) {
        s  += __shfl_down(s,  off, 64);
        s2 += __shfl_down(s2, off, 64);
    }

    __shared__ double sh[2][NTHR / 64];
    __shared__ unsigned int vsh;
    int wave = threadIdx.x >> 6;
    int lane = threadIdx.x & 63;
    if (lane == 0) { sh[0][wave] = s; sh[1][wave] = s2; }
    __syncthreads();

    if (threadIdx.x == 0) {
        double ts = 0.0, ts2 = 0.0;
        #pragma unroll
        for (int wv = 0; wv < NTHR / 64; ++wv) { ts += sh[0][wv]; ts2 += sh[1][wv]; }
        // agent-scope pair store, then release-increment of our own flag
        __hip_atomic_store(&pairs[2 * blockIdx.x],     ts,
                           __ATOMIC_RELAXED, __HIP_MEMORY_SCOPE_AGENT);
        __hip_atomic_store(&pairs[2 * blockIdx.x + 1], ts2,
                           __ATOMIC_RELAXED, __HIP_MEMORY_SCOPE_AGENT);
        unsigned v = __hip_atomic_fetch_add(&flags[blockIdx.x], 1u,
                           __ATOMIC_RELEASE, __HIP_MEMORY_SCOPE_AGENT) + 1u;
        if (blockIdx.x == 0) vsh = v;
    }
    __syncthreads();

    if (blockIdx.x == 0) {
        unsigned v = vsh;
        int t = threadIdx.x;
        // spin until all 512 flags reach v (2 flags per thread), bounded
        #pragma unroll
        for (int p = 0; p < NBLK / NTHR; ++p) {
            int q = t + p * NTHR;
            int iter = 0;
            while (true) {
                unsigned f = __hip_atomic_load(&flags[q],
                                __ATOMIC_ACQUIRE, __HIP_MEMORY_SCOPE_AGENT);
                if ((int)(f - v) >= 0) break;          // reached (wrap-safe)
                if (++iter > (1 << 20)) break;         // bounded: no hang
            }
        }
        __syncthreads();

        double a = 0.0, b = 0.0;
        #pragma unroll
        for (int p = 0; p < NBLK / NTHR; ++p) {
            int q = t + p * NTHR;
            a += __hip_atomic_load(&pairs[2 * q],
                                   __ATOMIC_RELAXED, __HIP_MEMORY_SCOPE_AGENT);
            b += __hip_atomic_load(&pairs[2 * q + 1],
                                   __ATOMIC_RELAXED, __HIP_MEMORY_SCOPE_AGENT);
        }
        #pragma unroll
        for (int off = 32; off > 0; off >>= 1) {
            a += __shfl_down(a, off, 64);
            b += __shfl_down(b, off, 64);
        }
        if (lane == 0) { sh[0][wave] = a; sh[1][wave] = b; }
        __syncthreads();
        if (threadIdx.x == 0) {
            double S = 0.0, S2 = 0.0;
            #pragma unroll
            for (int wv = 0; wv < NTHR / 64; ++wv) { S += sh[0][wv]; S2 += sh[1][wv]; }
            out[0] = (float)((S2 - S * S / M) / (M - 1.0));
        }
    }
}

extern "C" void kernel_launch(void* const* d_in, const int* in_sizes, int n_in,
                              void* d_out, int out_size, void* d_ws, size_t ws_size,
                              hipStream_t stream) {
    const float4* y  = (const float4*)d_in[0];
    const float4* yh = (const float4*)d_in[1];
    unsigned int* flags = (unsigned int*)d_ws;                  // 512 u32 = 2 KB
    double* pairs = (double*)((char*)d_ws + 4096);              // 512 pairs = 8 KB
    float* out = (float*)d_out;

    int n_elem = in_sizes[0];          // B*N*D = 8*1024*64 = 524288
    int n4 = n_elem / 4;               // 131072

    // M = B * N(N+1)/2 * D  (static expanded length of the repeat)
    const double B = 8.0, N = 1024.0, D = 64.0;
    double M = B * (N * (N + 1.0) * 0.5) * D;   // 268,697,600

    stoch_fused<<<NBLK, NTHR, 0, stream>>>(y, yh, flags, pairs, out, M, n4);
}

// Round 6
// 11.212 us; speedup vs baseline: 3.1993x; 1.1672x over previous
//
#include <hip/hip_runtime.h>

#define NTHR 256
#define NBLK 512   // NBLK * NTHR == n4 == 131072 (one float4 per thread)

// Stage 1: weighted sums S = sum(w * e), S2 = sum(w * e^2), e = (y - y_hat)^2,
// w = (row index along dim1) + 1. One float4 per thread, no loop.
__global__ __launch_bounds__(NTHR) void stoch_partial(
    const float4* __restrict__ y,
    const float4* __restrict__ yh,
    double* __restrict__ ws,
    int n4)
{
    int idx = blockIdx.x * NTHR + threadIdx.x;
    double s = 0.0, s2 = 0.0;

    if (idx < n4) {
        float4 a = y[idx];
        float4 b = yh[idx];
        // Layout: [B][N=1024][D=64] fp32 -> 16 float4 per (b,i) row.
        int i = (idx >> 4) & 1023;          // row index within dim 1
        double w = (double)(i + 1);
        float d0 = a.x - b.x, d1 = a.y - b.y, d2 = a.z - b.z, d3 = a.w - b.w;
        float e0 = d0 * d0, e1 = d1 * d1, e2 = d2 * d2, e3 = d3 * d3;
        s  = w * ((double)e0 + (double)e1 + (double)e2 + (double)e3);
        s2 = w * ((double)e0 * e0 + (double)e1 * e1
                + (double)e2 * e2 + (double)e3 * e3);
    }

    // wave-64 butterfly reduce
    #pragma unroll
    for (int off = 32; off > 0; off >>= 1) {
        s  += __shfl_down(s,  off, 64);
        s2 += __shfl_down(s2, off, 64);
    }

    __shared__ double sh[2][NTHR / 64];
    int wave = threadIdx.x >> 6;
    int lane = threadIdx.x & 63;
    if (lane == 0) { sh[0][wave] = s; sh[1][wave] = s2; }
    __syncthreads();

    if (threadIdx.x == 0) {
        double ts = 0.0, ts2 = 0.0;
        #pragma unroll
        for (int wv = 0; wv < NTHR / 64; ++wv) { ts += sh[0][wv]; ts2 += sh[1][wv]; }
        ws[2 * blockIdx.x]     = ts;
        ws[2 * blockIdx.x + 1] = ts2;
    }
}

// Stage 2: one wave reduces NBLK partial pairs, finishes the variance formula.
__global__ __launch_bounds__(64) void stoch_final(
    const double* __restrict__ ws,
    float* __restrict__ out,
    double M)
{
    int lane = threadIdx.x;                 // 64 threads, single wave
    double s = 0.0, s2 = 0.0;
    #pragma unroll
    for (int p = 0; p < NBLK / 64; ++p) {   // 8 independent pair loads per lane
        int q = lane + p * 64;
        s  += ws[2 * q];
        s2 += ws[2 * q + 1];
    }

    #pragma unroll
    for (int off = 32; off > 0; off >>= 1) {
        s  += __shfl_down(s,  off, 64);
        s2 += __shfl_down(s2, off, 64);
    }

    if (lane == 0) {
        double var = (s2 - s * s / M) / (M - 1.0);
        out[0] = (float)var;
    }
}

extern "C" void kernel_launch(void* const* d_in, const int* in_sizes, int n_in,
                              void* d_out, int out_size, void* d_ws, size_t ws_size,
                              hipStream_t stream) {
    const float4* y  = (const float4*)d_in[0];
    const float4* yh = (const float4*)d_in[1];
    double* ws = (double*)d_ws;
    float* out = (float*)d_out;

    const int n_elem = in_sizes[0];         // B*N*D = 8*1024*64 = 524288
    const int n4 = n_elem / 4;              // 131072

    // M = B * N(N+1)/2 * D  (static expanded length of the repeat)
    const double B = 8.0, N = 1024.0, D = 64.0;
    const double M = B * (N * (N + 1.0) * 0.5) * D;   // 268,697,600

    stoch_partial<<<NBLK, NTHR, 0, stream>>>(y, yh, ws, n4);
    stoch_final<<<1, 64, 0, stream>>>(ws, out, M);
}